// Round 1
// baseline (456.558 us; speedup 1.0000x reference)
//
#include <hip/hip_runtime.h>
#include <hip/hip_fp16.h>

// HashGrid encode: N=524288, L=16, F=2, T=2^19.
// R7 (this session R1): occupancy attack.
//  - hg_main (VGPR=152 -> 3 waves/SIMD, 12 waves/CU, Occ 11.5%) split into
//    hg_lo (dense 0..5 + hash 6..7, cap 64 VGPR via __launch_bounds__(256,8))
//    and hg_hi (hash 8..15, cap ~85 via (256,6)), 1 point/thread,
//    level-pair processing + immediate float4 store to keep live state small.
//  - preprocessing fused into one hg_prep launch; quad grid flattened
//    (12456 -> 3372 useful blocks).

#define HG_L     16
#define HG_LOG_T 19
#define HG_T     (1u << HG_LOG_T)
#define HG_N     524288u
#define HP1      2654435761u
#define HP2      805459861u

// dense levels 0..5: resolution {16,22,30,42,58,80} -> S = res+1
#define DS0 17u
#define DS1 23u
#define DS2 31u
#define DS3 43u
#define DS4 59u
#define DS5 81u
#define DOFF0 0u
#define DOFF1 4913u      // +17^3
#define DOFF2 17080u     // +23^3
#define DOFF3 46871u     // +31^3
#define DOFF4 126378u    // +43^3
#define DOFF5 331757u    // +59^3
#define DTOTAL 863198u   // +81^3  (cells; 16 B each = 13.81 MB)

#define TAB_BYTES ((size_t)HG_L * HG_T * 4u)   // 32 MiB hashed region in ws

#define NB_INTER 5120u                          // (10*T/4)/256
#define NB_QUAD  3372u                          // ceil(DTOTAL/256)

__device__ __forceinline__ unsigned pack_h2(float f0, float f1) {
    __half2 h = __floats2half2_rn(f0, f1);
    return *reinterpret_cast<unsigned*>(&h);
}

// Fused preprocessing: blocks [0, NB_INTER) interleave hashed levels 6..15
// into half2 pair-table; blocks [NB_INTER, NB_INTER+NB_QUAD) build dense
// quad lattices for levels 0..5.
__global__ __launch_bounds__(256) void hg_prep(
    const float* __restrict__ hm,   // [L, F, T]
    __half2* __restrict__ wst,      // [L, T] (levels 6..15 written)
    uint4* __restrict__ quad)       // [DTOTAL]
{
    const unsigned bid = blockIdx.x;
    if (bid < NB_INTER) {
        const unsigned u = 6u * HG_T + (bid * 256u + threadIdx.x) * 4u;
        const unsigned l = u >> HG_LOG_T;
        const unsigned t = u & (HG_T - 1u);
        const float* base = hm + (size_t)l * (2u * HG_T);
        const float4 a = *reinterpret_cast<const float4*>(base + t);          // f=0
        const float4 b = *reinterpret_cast<const float4*>(base + HG_T + t);   // f=1
        uint4 o;
        o.x = pack_h2(a.x, b.x);
        o.y = pack_h2(a.y, b.y);
        o.z = pack_h2(a.z, b.z);
        o.w = pack_h2(a.w, b.w);
        *reinterpret_cast<uint4*>(wst + u) = o;
        return;
    }
    const unsigned j = (bid - NB_INTER) * 256u + threadIdx.x;
    if (j >= DTOTAL) return;
    unsigned l, S, off;
    if      (j < DOFF1) { l = 0; S = DS0; off = DOFF0; }
    else if (j < DOFF2) { l = 1; S = DS1; off = DOFF1; }
    else if (j < DOFF3) { l = 2; S = DS2; off = DOFF2; }
    else if (j < DOFF4) { l = 3; S = DS3; off = DOFF3; }
    else if (j < DOFF5) { l = 4; S = DS4; off = DOFF4; }
    else                { l = 5; S = DS5; off = DOFF5; }
    const unsigned i  = j - off;
    const unsigned x  = i % S;
    const unsigned t1 = i / S;
    const unsigned y  = t1 % S;
    const unsigned z  = t1 / S;
    const unsigned M = HG_T - 1u;
    const unsigned hz = z * HP2;
    const unsigned hy0 = y * HP1, hy1 = hy0 + HP1;
    const unsigned i00 = (hy0 ^ hz ^ x) & M;
    const unsigned i10 = (hy0 ^ hz ^ (x + 1u)) & M;
    const unsigned i01 = (hy1 ^ hz ^ x) & M;
    const unsigned i11 = (hy1 ^ hz ^ (x + 1u)) & M;
    const float* b0 = hm + (size_t)l * (2u * HG_T);
    uint4 o;
    o.x = pack_h2(b0[i00], b0[i00 + HG_T]);
    o.y = pack_h2(b0[i10], b0[i10 + HG_T]);
    o.z = pack_h2(b0[i01], b0[i01 + HG_T]);
    o.w = pack_h2(b0[i11], b0[i11 + HG_T]);
    quad[j] = o;
}

__device__ __forceinline__ float2 hfv(unsigned raw) {
    return __half22float2(*reinterpret_cast<const __half2*>(&raw));
}

template <unsigned S, unsigned OFF>
__device__ __forceinline__ float2 enc_dense(
    float px, float py, float pz, float res,
    const uint4* __restrict__ quad)
{
    const float xs0 = px * res, xs1 = py * res, xs2 = pz * res;
    const float fl0 = floorf(xs0), fl1 = floorf(xs1), fl2 = floorf(xs2);
    const float fr0 = xs0 - fl0, fr1 = xs1 - fl1, fr2 = xs2 - fl2;
    const unsigned x0 = (unsigned)fl0;
    const unsigned y0 = (unsigned)fl1;
    const unsigned z0 = (unsigned)fl2;

    const unsigned i = (z0 * S + y0) * S + x0 + OFF;
    const uint4 q0 = quad[i];             // z0 slab: v00,v10,v01,v11
    const uint4 q1 = quad[i + S * S];     // z0+1 slab

    const float w0x = 1.0f - fr0, w1x = fr0;
    const float w0y = 1.0f - fr1, w1y = fr1;
    const float w0z = 1.0f - fr2, w1z = fr2;

    const float2 a00 = hfv(q0.x), a10 = hfv(q0.y), a01 = hfv(q0.z), a11 = hfv(q0.w);
    const float2 b00 = hfv(q1.x), b10 = hfv(q1.y), b01 = hfv(q1.z), b11 = hfv(q1.w);

    // bilinear in (x,y) per z-slab, then lerp z
    const float s0x = w0y * (w0x * a00.x + w1x * a10.x) + w1y * (w0x * a01.x + w1x * a11.x);
    const float s0y = w0y * (w0x * a00.y + w1x * a10.y) + w1y * (w0x * a01.y + w1x * a11.y);
    const float s1x = w0y * (w0x * b00.x + w1x * b10.x) + w1y * (w0x * b01.x + w1x * b11.x);
    const float s1y = w0y * (w0x * b00.y + w1x * b10.y) + w1y * (w0x * b01.y + w1x * b11.y);

    return make_float2(w0z * s0x + w1z * s1x, w0z * s0y + w1z * s1y);
}

__device__ __forceinline__ float2 enc_hash(
    float px, float py, float pz, float res,
    const uint2* __restrict__ tab2)   // level's table as aligned pairs
{
    const float xs0 = px * res, xs1 = py * res, xs2 = pz * res;
    const float fl0 = floorf(xs0), fl1 = floorf(xs1), fl2 = floorf(xs2);
    const float fr0 = xs0 - fl0, fr1 = xs1 - fl1, fr2 = xs2 - fl2;
    const unsigned x0 = (unsigned)fl0;
    const unsigned y0 = (unsigned)fl1;
    const unsigned z0 = (unsigned)fl2;
    const unsigned M = HG_T - 1u;

    const unsigned hy0 = y0 * HP1, hy1 = hy0 + HP1;
    const unsigned hz0 = z0 * HP2, hz1 = hz0 + HP2;
    const unsigned H0 = hy0 ^ hz0;
    const unsigned H1 = hy1 ^ hz0;
    const unsigned H2 = hy0 ^ hz1;
    const unsigned H3 = hy1 ^ hz1;

    unsigned r0[4], r1[4];
    {
        const unsigned i0 = (H0 ^ x0) & M; const uint2 q = tab2[i0 >> 1];
        r0[0] = (i0 & 1u) ? q.y : q.x;  r1[0] = (i0 & 1u) ? q.x : q.y;
    }
    {
        const unsigned i0 = (H1 ^ x0) & M; const uint2 q = tab2[i0 >> 1];
        r0[1] = (i0 & 1u) ? q.y : q.x;  r1[1] = (i0 & 1u) ? q.x : q.y;
    }
    {
        const unsigned i0 = (H2 ^ x0) & M; const uint2 q = tab2[i0 >> 1];
        r0[2] = (i0 & 1u) ? q.y : q.x;  r1[2] = (i0 & 1u) ? q.x : q.y;
    }
    {
        const unsigned i0 = (H3 ^ x0) & M; const uint2 q = tab2[i0 >> 1];
        r0[3] = (i0 & 1u) ? q.y : q.x;  r1[3] = (i0 & 1u) ? q.x : q.y;
    }
    if (x0 & 1u) {   // partner corners wrong for odd x0: reload (masked lanes)
        const unsigned xp = x0 + 1u;
        { const unsigned i1 = (H0 ^ xp) & M; const uint2 q = tab2[i1 >> 1];
          r1[0] = (i1 & 1u) ? q.y : q.x; }
        { const unsigned i1 = (H1 ^ xp) & M; const uint2 q = tab2[i1 >> 1];
          r1[1] = (i1 & 1u) ? q.y : q.x; }
        { const unsigned i1 = (H2 ^ xp) & M; const uint2 q = tab2[i1 >> 1];
          r1[2] = (i1 & 1u) ? q.y : q.x; }
        { const unsigned i1 = (H3 ^ xp) & M; const uint2 q = tab2[i1 >> 1];
          r1[3] = (i1 & 1u) ? q.y : q.x; }
    }

    const float w0x = 1.0f - fr0, w1x = fr0;
    const float w00 = (1.0f - fr1) * (1.0f - fr2);
    const float w10 = fr1 * (1.0f - fr2);
    const float w01 = (1.0f - fr1) * fr2;
    const float w11 = fr1 * fr2;

    float ax = 0.0f, ay = 0.0f;
    { const float2 v0 = hfv(r0[0]), v1 = hfv(r1[0]);
      ax += w00 * (w0x * v0.x + w1x * v1.x);
      ay += w00 * (w0x * v0.y + w1x * v1.y); }
    { const float2 v0 = hfv(r0[1]), v1 = hfv(r1[1]);
      ax += w10 * (w0x * v0.x + w1x * v1.x);
      ay += w10 * (w0x * v0.y + w1x * v1.y); }
    { const float2 v0 = hfv(r0[2]), v1 = hfv(r1[2]);
      ax += w01 * (w0x * v0.x + w1x * v1.x);
      ay += w01 * (w0x * v0.y + w1x * v1.y); }
    { const float2 v0 = hfv(r0[3]), v1 = hfv(r1[3]);
      ax += w11 * (w0x * v0.x + w1x * v1.x);
      ay += w11 * (w0x * v0.y + w1x * v1.y); }
    return make_float2(ax, ay);
}

// Levels 0..7 -> out[p][0..15] (first 64 B line). 1 point/thread.
// Cap 64 VGPR (8 waves/SIMD): dense path is slim (2 loads + FMA per level).
__global__ __launch_bounds__(256, 8) void hg_lo(
    const float* __restrict__ x,          // [N, 3]
    const uint2* __restrict__ tab2,       // hashed pair table [L*T/2]
    const uint4* __restrict__ quad,       // dense quad lattices [DTOTAL]
    const float* __restrict__ resolution, // [L]
    float*       __restrict__ out)        // [N, 32]
{
    const unsigned p = blockIdx.x * 256u + threadIdx.x;
    const float ax = x[p * 3 + 0], ay = x[p * 3 + 1], az = x[p * 3 + 2];
    float4* d = reinterpret_cast<float4*>(out + (size_t)p * 32u);
    {
        const float2 a = enc_dense<DS0, DOFF0>(ax, ay, az, resolution[0], quad);
        const float2 b = enc_dense<DS1, DOFF1>(ax, ay, az, resolution[1], quad);
        d[0] = make_float4(a.x, a.y, b.x, b.y);
    }
    {
        const float2 a = enc_dense<DS2, DOFF2>(ax, ay, az, resolution[2], quad);
        const float2 b = enc_dense<DS3, DOFF3>(ax, ay, az, resolution[3], quad);
        d[1] = make_float4(a.x, a.y, b.x, b.y);
    }
    {
        const float2 a = enc_dense<DS4, DOFF4>(ax, ay, az, resolution[4], quad);
        const float2 b = enc_dense<DS5, DOFF5>(ax, ay, az, resolution[5], quad);
        d[2] = make_float4(a.x, a.y, b.x, b.y);
    }
    {
        const float2 a = enc_hash(ax, ay, az, resolution[6], tab2 + 6u * (HG_T / 2u));
        const float2 b = enc_hash(ax, ay, az, resolution[7], tab2 + 7u * (HG_T / 2u));
        d[3] = make_float4(a.x, a.y, b.x, b.y);
    }
}

// Levels 8..15 -> out[p][16..31] (second 64 B line). 1 point/thread.
// Cap ~85 VGPR (6 waves/SIMD) — pure-hash path has more live loads.
__global__ __launch_bounds__(256, 6) void hg_hi(
    const float* __restrict__ x,
    const uint2* __restrict__ tab2,
    const float* __restrict__ resolution,
    float*       __restrict__ out)
{
    const unsigned p = blockIdx.x * 256u + threadIdx.x;
    const float ax = x[p * 3 + 0], ay = x[p * 3 + 1], az = x[p * 3 + 2];
    float4* d = reinterpret_cast<float4*>(out + (size_t)p * 32u + 16u);
#pragma unroll
    for (int pr = 0; pr < 4; ++pr) {
        const int l0 = 8 + 2 * pr;
        const float2 a = enc_hash(ax, ay, az, resolution[l0],
                                  tab2 + (size_t)l0 * (HG_T / 2u));
        const float2 b = enc_hash(ax, ay, az, resolution[l0 + 1],
                                  tab2 + (size_t)(l0 + 1) * (HG_T / 2u));
        d[pr] = make_float4(a.x, a.y, b.x, b.y);
    }
}

extern "C" void kernel_launch(void* const* d_in, const int* in_sizes, int n_in,
                              void* d_out, int out_size, void* d_ws, size_t ws_size,
                              hipStream_t stream) {
    const float* x          = (const float*)d_in[0];
    const float* hashmap    = (const float*)d_in[1];
    const float* resolution = (const float*)d_in[2];
    float* out              = (float*)d_out;

    __half2* wst  = (__half2*)d_ws;                              // 32 MiB hashed region
    uint4*   quad = (uint4*)((char*)d_ws + TAB_BYTES);           // 13.8 MB quads

    hipLaunchKernelGGL(hg_prep, dim3(NB_INTER + NB_QUAD), dim3(256), 0, stream,
                       hashmap, wst, quad);

    hipLaunchKernelGGL(hg_lo, dim3(HG_N / 256u), dim3(256), 0, stream,
                       x, (const uint2*)d_ws, quad, resolution, out);
    hipLaunchKernelGGL(hg_hi, dim3(HG_N / 256u), dim3(256), 0, stream,
                       x, (const uint2*)d_ws, resolution, out);
}

// Round 3
// 363.265 us; speedup vs baseline: 1.2568x; 1.2568x over previous
//
#include <hip/hip_runtime.h>
#include <hip/hip_fp16.h>

// HashGrid encode: N=524288, L=16, F=2, T=2^19.
// R8 resubmit (session R3): L2-residency pass structure. R2 bench died on an
// infra error (container acquire failed twice) before running; same design.
//  R1 post-mortem: occupancy fix worked (11.5%->59%) but exposed the real
//  limiter: L2 thrash. hg_hi fetched 748 MB (vs 481 MB for ALL levels in the
//  old fused kernel) because 8 hashed tables (16 MB) were live at once vs
//  4 MiB L2/XCD. Each 2 MB table has ~8x statistical reuse (4.2M corner
//  lookups into 524K entries) -- captured only while resident.
//  Fix: one kernel pass per LEVEL PAIR (2+2 MB = one XCD L2). Stream order
//  gives a hard barrier between passes, so the instantaneous working set is
//  always <= 4 MB (except dense level-5 pass, 11.8 MB, tolerated).
//  Passes: prep | dense 0-3 -> d0,d1 | dense 4-5 -> d2 | hash {6,7}..{14,15}
//  -> d3..d7. All passes 1 pt/thread, slim VGPR, 8 waves/SIMD.

#define HG_L     16
#define HG_LOG_T 19
#define HG_T     (1u << HG_LOG_T)
#define HG_N     524288u
#define HP1      2654435761u
#define HP2      805459861u

// dense levels 0..5: resolution {16,22,30,42,58,80} -> S = res+1
#define DS0 17u
#define DS1 23u
#define DS2 31u
#define DS3 43u
#define DS4 59u
#define DS5 81u
#define DOFF0 0u
#define DOFF1 4913u      // +17^3
#define DOFF2 17080u     // +23^3
#define DOFF3 46871u     // +31^3
#define DOFF4 126378u    // +43^3
#define DOFF5 331757u    // +59^3
#define DTOTAL 863198u   // +81^3  (cells; 16 B each = 13.81 MB)

#define TAB_BYTES ((size_t)HG_L * HG_T * 4u)   // 32 MiB hashed region in ws

#define NB_INTER 5120u                          // (10*T/4)/256
#define NB_QUAD  3372u                          // ceil(DTOTAL/256)

__device__ __forceinline__ unsigned pack_h2(float f0, float f1) {
    __half2 h = __floats2half2_rn(f0, f1);
    return *reinterpret_cast<unsigned*>(&h);
}

// Fused preprocessing: blocks [0, NB_INTER) interleave hashed levels 6..15
// into half2 pair-table; blocks [NB_INTER, NB_INTER+NB_QUAD) build dense
// quad lattices for levels 0..5.
__global__ __launch_bounds__(256) void hg_prep(
    const float* __restrict__ hm,   // [L, F, T]
    __half2* __restrict__ wst,      // [L, T] (levels 6..15 written)
    uint4* __restrict__ quad)       // [DTOTAL]
{
    const unsigned bid = blockIdx.x;
    if (bid < NB_INTER) {
        const unsigned u = 6u * HG_T + (bid * 256u + threadIdx.x) * 4u;
        const unsigned l = u >> HG_LOG_T;
        const unsigned t = u & (HG_T - 1u);
        const float* base = hm + (size_t)l * (2u * HG_T);
        const float4 a = *reinterpret_cast<const float4*>(base + t);          // f=0
        const float4 b = *reinterpret_cast<const float4*>(base + HG_T + t);   // f=1
        uint4 o;
        o.x = pack_h2(a.x, b.x);
        o.y = pack_h2(a.y, b.y);
        o.z = pack_h2(a.z, b.z);
        o.w = pack_h2(a.w, b.w);
        *reinterpret_cast<uint4*>(wst + u) = o;
        return;
    }
    const unsigned j = (bid - NB_INTER) * 256u + threadIdx.x;
    if (j >= DTOTAL) return;
    unsigned l, S, off;
    if      (j < DOFF1) { l = 0; S = DS0; off = DOFF0; }
    else if (j < DOFF2) { l = 1; S = DS1; off = DOFF1; }
    else if (j < DOFF3) { l = 2; S = DS2; off = DOFF2; }
    else if (j < DOFF4) { l = 3; S = DS3; off = DOFF3; }
    else if (j < DOFF5) { l = 4; S = DS4; off = DOFF4; }
    else                { l = 5; S = DS5; off = DOFF5; }
    const unsigned i  = j - off;
    const unsigned x  = i % S;
    const unsigned t1 = i / S;
    const unsigned y  = t1 % S;
    const unsigned z  = t1 / S;
    const unsigned M = HG_T - 1u;
    const unsigned hz = z * HP2;
    const unsigned hy0 = y * HP1, hy1 = hy0 + HP1;
    const unsigned i00 = (hy0 ^ hz ^ x) & M;
    const unsigned i10 = (hy0 ^ hz ^ (x + 1u)) & M;
    const unsigned i01 = (hy1 ^ hz ^ x) & M;
    const unsigned i11 = (hy1 ^ hz ^ (x + 1u)) & M;
    const float* b0 = hm + (size_t)l * (2u * HG_T);
    uint4 o;
    o.x = pack_h2(b0[i00], b0[i00 + HG_T]);
    o.y = pack_h2(b0[i10], b0[i10 + HG_T]);
    o.z = pack_h2(b0[i01], b0[i01 + HG_T]);
    o.w = pack_h2(b0[i11], b0[i11 + HG_T]);
    quad[j] = o;
}

__device__ __forceinline__ float2 hfv(unsigned raw) {
    return __half22float2(*reinterpret_cast<const __half2*>(&raw));
}

template <unsigned S, unsigned OFF>
__device__ __forceinline__ float2 enc_dense(
    float px, float py, float pz, float res,
    const uint4* __restrict__ quad)
{
    const float xs0 = px * res, xs1 = py * res, xs2 = pz * res;
    const float fl0 = floorf(xs0), fl1 = floorf(xs1), fl2 = floorf(xs2);
    const float fr0 = xs0 - fl0, fr1 = xs1 - fl1, fr2 = xs2 - fl2;
    const unsigned x0 = (unsigned)fl0;
    const unsigned y0 = (unsigned)fl1;
    const unsigned z0 = (unsigned)fl2;

    const unsigned i = (z0 * S + y0) * S + x0 + OFF;
    const uint4 q0 = quad[i];             // z0 slab: v00,v10,v01,v11
    const uint4 q1 = quad[i + S * S];     // z0+1 slab

    const float w0x = 1.0f - fr0, w1x = fr0;
    const float w0y = 1.0f - fr1, w1y = fr1;
    const float w0z = 1.0f - fr2, w1z = fr2;

    const float2 a00 = hfv(q0.x), a10 = hfv(q0.y), a01 = hfv(q0.z), a11 = hfv(q0.w);
    const float2 b00 = hfv(q1.x), b10 = hfv(q1.y), b01 = hfv(q1.z), b11 = hfv(q1.w);

    // bilinear in (x,y) per z-slab, then lerp z
    const float s0x = w0y * (w0x * a00.x + w1x * a10.x) + w1y * (w0x * a01.x + w1x * a11.x);
    const float s0y = w0y * (w0x * a00.y + w1x * a10.y) + w1y * (w0x * a01.y + w1x * a11.y);
    const float s1x = w0y * (w0x * b00.x + w1x * b10.x) + w1y * (w0x * b01.x + w1x * b11.x);
    const float s1y = w0y * (w0x * b00.y + w1x * b10.y) + w1y * (w0x * b01.y + w1x * b11.y);

    return make_float2(w0z * s0x + w1z * s1x, w0z * s0y + w1z * s1y);
}

__device__ __forceinline__ float2 enc_hash(
    float px, float py, float pz, float res,
    const uint2* __restrict__ tab2)   // level's table as aligned pairs
{
    const float xs0 = px * res, xs1 = py * res, xs2 = pz * res;
    const float fl0 = floorf(xs0), fl1 = floorf(xs1), fl2 = floorf(xs2);
    const float fr0 = xs0 - fl0, fr1 = xs1 - fl1, fr2 = xs2 - fl2;
    const unsigned x0 = (unsigned)fl0;
    const unsigned y0 = (unsigned)fl1;
    const unsigned z0 = (unsigned)fl2;
    const unsigned M = HG_T - 1u;

    const unsigned hy0 = y0 * HP1, hy1 = hy0 + HP1;
    const unsigned hz0 = z0 * HP2, hz1 = hz0 + HP2;
    const unsigned H0 = hy0 ^ hz0;
    const unsigned H1 = hy1 ^ hz0;
    const unsigned H2 = hy0 ^ hz1;
    const unsigned H3 = hy1 ^ hz1;

    unsigned r0[4], r1[4];
    {
        const unsigned i0 = (H0 ^ x0) & M; const uint2 q = tab2[i0 >> 1];
        r0[0] = (i0 & 1u) ? q.y : q.x;  r1[0] = (i0 & 1u) ? q.x : q.y;
    }
    {
        const unsigned i0 = (H1 ^ x0) & M; const uint2 q = tab2[i0 >> 1];
        r0[1] = (i0 & 1u) ? q.y : q.x;  r1[1] = (i0 & 1u) ? q.x : q.y;
    }
    {
        const unsigned i0 = (H2 ^ x0) & M; const uint2 q = tab2[i0 >> 1];
        r0[2] = (i0 & 1u) ? q.y : q.x;  r1[2] = (i0 & 1u) ? q.x : q.y;
    }
    {
        const unsigned i0 = (H3 ^ x0) & M; const uint2 q = tab2[i0 >> 1];
        r0[3] = (i0 & 1u) ? q.y : q.x;  r1[3] = (i0 & 1u) ? q.x : q.y;
    }
    if (x0 & 1u) {   // partner corners wrong for odd x0: reload (masked lanes)
        const unsigned xp = x0 + 1u;
        { const unsigned i1 = (H0 ^ xp) & M; const uint2 q = tab2[i1 >> 1];
          r1[0] = (i1 & 1u) ? q.y : q.x; }
        { const unsigned i1 = (H1 ^ xp) & M; const uint2 q = tab2[i1 >> 1];
          r1[1] = (i1 & 1u) ? q.y : q.x; }
        { const unsigned i1 = (H2 ^ xp) & M; const uint2 q = tab2[i1 >> 1];
          r1[2] = (i1 & 1u) ? q.y : q.x; }
        { const unsigned i1 = (H3 ^ xp) & M; const uint2 q = tab2[i1 >> 1];
          r1[3] = (i1 & 1u) ? q.y : q.x; }
    }

    const float w0x = 1.0f - fr0, w1x = fr0;
    const float w00 = (1.0f - fr1) * (1.0f - fr2);
    const float w10 = fr1 * (1.0f - fr2);
    const float w01 = (1.0f - fr1) * fr2;
    const float w11 = fr1 * fr2;

    float ax = 0.0f, ay = 0.0f;
    { const float2 v0 = hfv(r0[0]), v1 = hfv(r1[0]);
      ax += w00 * (w0x * v0.x + w1x * v1.x);
      ay += w00 * (w0x * v0.y + w1x * v1.y); }
    { const float2 v0 = hfv(r0[1]), v1 = hfv(r1[1]);
      ax += w10 * (w0x * v0.x + w1x * v1.x);
      ay += w10 * (w0x * v0.y + w1x * v1.y); }
    { const float2 v0 = hfv(r0[2]), v1 = hfv(r1[2]);
      ax += w01 * (w0x * v0.x + w1x * v1.x);
      ay += w01 * (w0x * v0.y + w1x * v1.y); }
    { const float2 v0 = hfv(r0[3]), v1 = hfv(r1[3]);
      ax += w11 * (w0x * v0.x + w1x * v1.x);
      ay += w11 * (w0x * v0.y + w1x * v1.y); }
    return make_float2(ax, ay);
}

// Pass: dense levels 0..3 -> d0,d1. Tables = 2.1 MB quads (L2-resident).
__global__ __launch_bounds__(256, 8) void hg_d01(
    const float* __restrict__ x,
    const uint4* __restrict__ quad,
    const float* __restrict__ resolution,
    float*       __restrict__ out)
{
    const unsigned p = blockIdx.x * 256u + threadIdx.x;
    const float ax = x[p * 3 + 0], ay = x[p * 3 + 1], az = x[p * 3 + 2];
    const float2 a = enc_dense<DS0, DOFF0>(ax, ay, az, resolution[0], quad);
    const float2 b = enc_dense<DS1, DOFF1>(ax, ay, az, resolution[1], quad);
    const float2 c = enc_dense<DS2, DOFF2>(ax, ay, az, resolution[2], quad);
    const float2 e = enc_dense<DS3, DOFF3>(ax, ay, az, resolution[3], quad);
    float4* d = reinterpret_cast<float4*>(out + (size_t)p * 32u);
    d[0] = make_float4(a.x, a.y, b.x, b.y);
    d[1] = make_float4(c.x, c.y, e.x, e.y);
}

// Pass: dense levels 4..5 -> d2. Working set 11.8 MB (partial residency).
__global__ __launch_bounds__(256, 8) void hg_d2(
    const float* __restrict__ x,
    const uint4* __restrict__ quad,
    const float* __restrict__ resolution,
    float*       __restrict__ out)
{
    const unsigned p = blockIdx.x * 256u + threadIdx.x;
    const float ax = x[p * 3 + 0], ay = x[p * 3 + 1], az = x[p * 3 + 2];
    const float2 a = enc_dense<DS4, DOFF4>(ax, ay, az, resolution[4], quad);
    const float2 b = enc_dense<DS5, DOFF5>(ax, ay, az, resolution[5], quad);
    reinterpret_cast<float4*>(out + (size_t)p * 32u)[2] =
        make_float4(a.x, a.y, b.x, b.y);
}

// Pass: hashed level pair {L0, L0+1} -> d[L0/2]. Tables = 4 MB = one XCD L2.
template <int L0>
__global__ __launch_bounds__(256, 8) void hg_hpass(
    const float* __restrict__ x,
    const uint2* __restrict__ tab2,
    const float* __restrict__ resolution,
    float*       __restrict__ out)
{
    const unsigned p = blockIdx.x * 256u + threadIdx.x;
    const float ax = x[p * 3 + 0], ay = x[p * 3 + 1], az = x[p * 3 + 2];
    const float2 a = enc_hash(ax, ay, az, resolution[L0],
                              tab2 + (size_t)L0 * (HG_T / 2u));
    const float2 b = enc_hash(ax, ay, az, resolution[L0 + 1],
                              tab2 + (size_t)(L0 + 1) * (HG_T / 2u));
    reinterpret_cast<float4*>(out + (size_t)p * 32u)[L0 / 2] =
        make_float4(a.x, a.y, b.x, b.y);
}

extern "C" void kernel_launch(void* const* d_in, const int* in_sizes, int n_in,
                              void* d_out, int out_size, void* d_ws, size_t ws_size,
                              hipStream_t stream) {
    const float* x          = (const float*)d_in[0];
    const float* hashmap    = (const float*)d_in[1];
    const float* resolution = (const float*)d_in[2];
    float* out              = (float*)d_out;

    __half2* wst  = (__half2*)d_ws;                              // 32 MiB hashed region
    uint4*   quad = (uint4*)((char*)d_ws + TAB_BYTES);           // 13.8 MB quads
    const uint2* tab2 = (const uint2*)d_ws;

    hipLaunchKernelGGL(hg_prep, dim3(NB_INTER + NB_QUAD), dim3(256), 0, stream,
                       hashmap, wst, quad);

    const dim3 g(HG_N / 256u), b(256);
    hipLaunchKernelGGL(hg_d01,      g, b, 0, stream, x, quad, resolution, out);
    hipLaunchKernelGGL(hg_d2,       g, b, 0, stream, x, quad, resolution, out);
    hipLaunchKernelGGL(hg_hpass< 6>, g, b, 0, stream, x, tab2, resolution, out);
    hipLaunchKernelGGL(hg_hpass< 8>, g, b, 0, stream, x, tab2, resolution, out);
    hipLaunchKernelGGL(hg_hpass<10>, g, b, 0, stream, x, tab2, resolution, out);
    hipLaunchKernelGGL(hg_hpass<12>, g, b, 0, stream, x, tab2, resolution, out);
    hipLaunchKernelGGL(hg_hpass<14>, g, b, 0, stream, x, tab2, resolution, out);
}